// Round 1
// baseline (687.755 us; speedup 1.0000x reference)
//
#include <hip/hip_runtime.h>
#include <math.h>

// ---------------------------------------------------------------------------
// KarplusStrong: spectral-domain reformulation.
//
// filt(b, tf) = irfft_ortho(rfft_ortho(b) * tf) * w  ==  irfft(rfft(b)*tf) * w
// (default norms; ortho factors cancel). Hamming (periodic) has 3 spectral
// taps: w[n] = 0.54 - 0.23 e^{i2pi n/512} - 0.23 e^{-i2pi n/512}, so
//   C_t = Wconv3( tf_t ⊙ (C_{t-1} + P_t) ),  P_t = rfft(imps_t)
// with Wconv3(V)[k] = 0.54 V[k] - 0.23 (V[k-1] + V[k+1]) (hermitian edges).
// pocketfft irfft ignores Im at bins 0 and 256 -> force Im(V)=0 there.
//
// ||A_t|| <= max|w| * max|tf| < 0.2*sqrt(2) = 0.283  => contraction.
// 0.283^16 ~ 1.6e-9, so chunks of 64 frames run independently with a
// 16-step zero-state warmup: 512-way parallelism for the "sequential" scan.
//
// Workspace: P (32768x257 float2) + C (32768x257 float2) = 134,742,016 B.
// ---------------------------------------------------------------------------

#define N_ITER   32768
#define NBINS    257
#define BLOCK_N  512
#define KWARM    16
#define FCH      64
#define NCHUNK   (N_ITER / FCH)     // 512
#define OUT_LEN  8388608

__device__ __forceinline__ int brev9(int x) { return (int)(__brev((unsigned)x) >> 23); }
// LDS pad map to break power-of-2 bank patterns (injective relabeling).
__device__ __forceinline__ int PD(int i) { return i + (i >> 4); }
#define FBSZ 544   // PD(511) = 542

// In-place radix-2 DIF over one wave's 512-pt buffer. Natural input,
// bit-reversed output. tsign=+1: forward DFT; tsign=-1: unnormalized IDFT.
__device__ __forceinline__ void dif_stages(float2* fb, const float2* tw, int lane, float tsign) {
  #pragma unroll
  for (int s = 8; s >= 0; --s) {
    const int m = 1 << s;
    #pragma unroll
    for (int r = 0; r < 4; ++r) {
      int p = r * 64 + lane;
      int q = p & (m - 1);
      int i = ((p >> s) << (s + 1)) + q;
      float2 a = fb[PD(i)];
      float2 c = fb[PD(i + m)];
      fb[PD(i)] = make_float2(a.x + c.x, a.y + c.y);
      float dr = a.x - c.x, di = a.y - c.y;
      float2 t = tw[q << (8 - s)];
      float twr = t.x, twi = tsign * t.y;
      fb[PD(i + m)] = make_float2(dr * twr - di * twi, dr * twi + di * twr);
    }
    __syncthreads();
  }
}

// K1: P_t = rfft(imps_t), imps_t = (2*noise-1)*env[t]^2. One wave per frame.
__global__ __launch_bounds__(256) void ks_fwd_fft(const float* __restrict__ noise,
                                                  const float* __restrict__ env,
                                                  float2* __restrict__ P) {
  __shared__ float2 tw[256];
  __shared__ float2 fb[4][FBSZ];
  const int tid = threadIdx.x;
  const int w = tid >> 6, lane = tid & 63;
  if (tid < 256) {
    float ang = -6.28318530717958647692f * (float)tid / 512.0f;
    float sv, cv; sincosf(ang, &sv, &cv);
    tw[tid] = make_float2(cv, sv);
  }
  const int t = blockIdx.x * 4 + w;
  const float e = env[t];
  const float e2 = e * e;
  #pragma unroll
  for (int r = 0; r < 8; ++r) {
    int n = r * 64 + lane;
    float x = 2.0f * noise[(size_t)t * BLOCK_N + n] - 1.0f;
    fb[w][PD(n)] = make_float2(x * e2, 0.0f);
  }
  __syncthreads();
  dif_stages(fb[w], tw, lane, 1.0f);
  #pragma unroll
  for (int r = 0; r < 5; ++r) {
    int kk = r * 64 + lane;
    if (kk < NBINS) P[(size_t)t * NBINS + kk] = fb[w][PD(brev9(kk))];
  }
}

// K2: chunked spectral recurrence. Block j produces C_t for t in [64j, 64j+64)
// after a 16-step zero-state warmup (chunk 0 is exact from t=0).
// 257 active threads <-> bins; 1 barrier/step (double-buffered V).
__global__ __launch_bounds__(320) void ks_recur(const float* __restrict__ tfr,
                                                const float* __restrict__ tfi,
                                                const float2* __restrict__ P,
                                                float2* __restrict__ Cws) {
  __shared__ float2 V[2][NBINS];
  const int j = blockIdx.x;
  const int k = threadIdx.x;
  const bool act = (k < NBINS);
  const int tprod = j * FCH;
  const int t0 = (j == 0) ? 0 : (tprod - KWARM);
  const int tend = tprod + FCH;
  float Cr = 0.0f, Ci = 0.0f;
  float tr0 = 0.f, ti0 = 0.f, tr1 = 0.f, ti1 = 0.f;
  float2 p0 = make_float2(0.f, 0.f), p1 = make_float2(0.f, 0.f);
  if (act) {
    size_t a = (size_t)t0 * NBINS + k;
    tr0 = tfr[a]; ti0 = tfi[a]; p0 = P[a];
    size_t b = (size_t)(t0 + 1) * NBINS + k;
    tr1 = tfr[b]; ti1 = tfi[b]; p1 = P[b];
  }
  int pb = 0;
  for (int t = t0; t < tend; ++t) {
    const float trc = tr0, tic = ti0;
    const float2 pc = p0;
    tr0 = tr1; ti0 = ti1; p0 = p1;          // rotate pipeline
    int tn = t + 2; if (tn > N_ITER - 1) tn = N_ITER - 1;
    if (act) {                               // prefetch t+2
      size_t a = (size_t)tn * NBINS + k;
      tr1 = tfr[a]; ti1 = tfi[a]; p1 = P[a];
    }
    float Vr = 0.0f, Vi = 0.0f;
    if (act) {
      float Ur = Cr + pc.x, Ui = Ci + pc.y;
      Vr = trc * Ur - tic * Ui;
      Vi = trc * Ui + tic * Ur;
      if (k == 0 || k == 256) Vi = 0.0f;     // pocketfft c2r ignores edge imag
      V[pb][k] = make_float2(Vr, Vi);
    }
    __syncthreads();
    if (act) {
      float2 L = (k == 0)   ? V[pb][1]   : V[pb][k - 1];
      float Ly = (k == 0)   ? -L.y : L.y;    // left of DC = conj(V[1])
      float2 R = (k == 256) ? V[pb][255] : V[pb][k + 1];
      float Ry = (k == 256) ? -R.y : R.y;    // right of Nyq = conj(V[255])
      Cr = 0.54f * Vr - 0.23f * (L.x + R.x);
      Ci = 0.54f * Vi - 0.23f * (Ly + Ry);
      if (t >= tprod) Cws[(size_t)t * NBINS + k] = make_float2(Cr, Ci);
    }
    pb ^= 1;
  }
}

// K3: block b (>=1): upd_b = irfft(C_{b-1}) + imps_b ; block 0 = imps_0.
// Overlap-add (hop 256) via atomicAdd; block 32768 is fully truncated.
__global__ __launch_bounds__(256) void ks_inv_fft(const float2* __restrict__ Cws,
                                                  const float* __restrict__ noise,
                                                  const float* __restrict__ env,
                                                  float* __restrict__ out) {
  __shared__ float2 tw[256];
  __shared__ float2 fb[4][FBSZ];
  const int tid = threadIdx.x;
  const int w = tid >> 6, lane = tid & 63;
  if (tid < 256) {
    float ang = -6.28318530717958647692f * (float)tid / 512.0f;
    float sv, cv; sincosf(ang, &sv, &cv);
    tw[tid] = make_float2(cv, sv);
  }
  const int b = blockIdx.x * 4 + w;
  const int row = (b == 0) ? 0 : (b - 1);    // b=0 runs FFT on row 0, discards
  #pragma unroll
  for (int r = 0; r < 5; ++r) {
    int kk = r * 64 + lane;
    if (kk < NBINS) {
      float2 c = Cws[(size_t)row * NBINS + kk];
      float zr = c.x * (1.0f / 512.0f), zi = c.y * (1.0f / 512.0f);
      fb[w][PD(kk)] = make_float2(zr, zi);
      if (kk >= 1 && kk <= 255) fb[w][PD(512 - kk)] = make_float2(zr, -zi);
    }
  }
  __syncthreads();
  dif_stages(fb[w], tw, lane, -1.0f);        // unnormalized IDFT, bitrev order
  const float e = env[b];
  const float e2 = e * e;
  #pragma unroll
  for (int r = 0; r < 8; ++r) {
    int p = r * 64 + lane;
    int n = brev9(p);
    float y = (b == 0) ? 0.0f : fb[w][PD(p)].x;
    float imp = (2.0f * noise[(size_t)b * BLOCK_N + n] - 1.0f) * e2;
    int addr = b * 256 + n;
    if (addr < OUT_LEN) atomicAdd(out + addr, y + imp);
  }
}

extern "C" void kernel_launch(void* const* d_in, const int* in_sizes, int n_in,
                              void* d_out, int out_size, void* d_ws, size_t ws_size,
                              hipStream_t stream) {
  (void)in_sizes; (void)n_in; (void)ws_size;
  const float* noise = (const float*)d_in[1];
  const float* env   = (const float*)d_in[2];
  const float* tfr   = (const float*)d_in[3];
  const float* tfi   = (const float*)d_in[4];
  float* out = (float*)d_out;

  float2* P   = (float2*)d_ws;
  float2* Cws = (float2*)((char*)d_ws + (size_t)N_ITER * NBINS * sizeof(float2));
  // ws requirement: 2 * 32768 * 257 * 8 = 134,742,016 bytes.

  hipMemsetAsync(d_out, 0, (size_t)out_size * sizeof(float), stream);
  ks_fwd_fft<<<dim3(N_ITER / 4), dim3(256), 0, stream>>>(noise, env, P);
  ks_recur<<<dim3(NCHUNK), dim3(320), 0, stream>>>(tfr, tfi, P, Cws);
  ks_inv_fft<<<dim3(N_ITER / 4), dim3(256), 0, stream>>>(Cws, noise, env, out);
}

// Round 2
// 343.512 us; speedup vs baseline: 2.0021x; 2.0021x over previous
//
#include <hip/hip_runtime.h>
#include <math.h>

// ---------------------------------------------------------------------------
// KarplusStrong: spectral-domain reformulation.
//
// filt(b, tf) = irfft_ortho(rfft_ortho(b) * tf) * w  ==  irfft(rfft(b)*tf) * w
// (default norms; ortho factors cancel). Hamming (periodic) has 3 spectral
// taps, so   C_t = Wconv3( tf_t ⊙ (C_{t-1} + P_t) ),  P_t = rfft(imps_t)
// with Wconv3(V)[k] = 0.54 V[k] - 0.23 (V[k-1] + V[k+1]) (hermitian edges).
// pocketfft irfft ignores Im at bins 0 and 256 -> force Im(V)=0 there.
//
// ||A_t|| <= max|w| * max|tf| < 0.283 => contraction; 0.283^16 ~ 1.6e-9, so
// chunks of 64 frames run independently with a 16-step zero-state warmup.
//
// R1: replaced atomic overlap-add (524 MB of 32B-granule atomic writes,
// 420 us) with (a) coalesced per-frame block store, (b) elementwise 2-tap
// overlap-add kernel. blk reuses the P region of the workspace.
// ---------------------------------------------------------------------------

#define N_ITER   32768
#define NBINS    257
#define BLOCK_N  512
#define KWARM    16
#define FCH      64
#define NCHUNK   (N_ITER / FCH)     // 512
#define OUT_LEN  8388608

__device__ __forceinline__ int brev9(int x) { return (int)(__brev((unsigned)x) >> 23); }
// LDS pad map to break power-of-2 bank patterns (injective relabeling).
__device__ __forceinline__ int PD(int i) { return i + (i >> 4); }
#define FBSZ 544   // PD(511) = 542

// In-place radix-2 DIF over one wave's 512-pt buffer. Natural input,
// bit-reversed output. tsign=+1: forward DFT; tsign=-1: unnormalized IDFT.
__device__ __forceinline__ void dif_stages(float2* fb, const float2* tw, int lane, float tsign) {
  #pragma unroll
  for (int s = 8; s >= 0; --s) {
    const int m = 1 << s;
    #pragma unroll
    for (int r = 0; r < 4; ++r) {
      int p = r * 64 + lane;
      int q = p & (m - 1);
      int i = ((p >> s) << (s + 1)) + q;
      float2 a = fb[PD(i)];
      float2 c = fb[PD(i + m)];
      fb[PD(i)] = make_float2(a.x + c.x, a.y + c.y);
      float dr = a.x - c.x, di = a.y - c.y;
      float2 t = tw[q << (8 - s)];
      float twr = t.x, twi = tsign * t.y;
      fb[PD(i + m)] = make_float2(dr * twr - di * twi, dr * twi + di * twr);
    }
    __syncthreads();
  }
}

// K1: P_t = rfft(imps_t), imps_t = (2*noise-1)*env[t]^2. One wave per frame.
__global__ __launch_bounds__(256) void ks_fwd_fft(const float* __restrict__ noise,
                                                  const float* __restrict__ env,
                                                  float2* __restrict__ P) {
  __shared__ float2 tw[256];
  __shared__ float2 fb[4][FBSZ];
  const int tid = threadIdx.x;
  const int w = tid >> 6, lane = tid & 63;
  if (tid < 256) {
    float ang = -6.28318530717958647692f * (float)tid / 512.0f;
    float sv, cv; sincosf(ang, &sv, &cv);
    tw[tid] = make_float2(cv, sv);
  }
  const int t = blockIdx.x * 4 + w;
  const float e = env[t];
  const float e2 = e * e;
  #pragma unroll
  for (int r = 0; r < 8; ++r) {
    int n = r * 64 + lane;
    float x = 2.0f * noise[(size_t)t * BLOCK_N + n] - 1.0f;
    fb[w][PD(n)] = make_float2(x * e2, 0.0f);
  }
  __syncthreads();
  dif_stages(fb[w], tw, lane, 1.0f);
  #pragma unroll
  for (int r = 0; r < 5; ++r) {
    int kk = r * 64 + lane;
    if (kk < NBINS) P[(size_t)t * NBINS + kk] = fb[w][PD(brev9(kk))];
  }
}

// K2: chunked spectral recurrence. Block j produces C_t for t in [64j, 64j+64)
// after a 16-step zero-state warmup (chunk 0 is exact from t=0).
__global__ __launch_bounds__(320) void ks_recur(const float* __restrict__ tfr,
                                                const float* __restrict__ tfi,
                                                const float2* __restrict__ P,
                                                float2* __restrict__ Cws) {
  __shared__ float2 V[2][NBINS];
  const int j = blockIdx.x;
  const int k = threadIdx.x;
  const bool act = (k < NBINS);
  const int tprod = j * FCH;
  const int t0 = (j == 0) ? 0 : (tprod - KWARM);
  const int tend = tprod + FCH;
  float Cr = 0.0f, Ci = 0.0f;
  float tr0 = 0.f, ti0 = 0.f, tr1 = 0.f, ti1 = 0.f;
  float2 p0 = make_float2(0.f, 0.f), p1 = make_float2(0.f, 0.f);
  if (act) {
    size_t a = (size_t)t0 * NBINS + k;
    tr0 = tfr[a]; ti0 = tfi[a]; p0 = P[a];
    size_t b = (size_t)(t0 + 1) * NBINS + k;
    tr1 = tfr[b]; ti1 = tfi[b]; p1 = P[b];
  }
  int pb = 0;
  for (int t = t0; t < tend; ++t) {
    const float trc = tr0, tic = ti0;
    const float2 pc = p0;
    tr0 = tr1; ti0 = ti1; p0 = p1;          // rotate pipeline
    int tn = t + 2; if (tn > N_ITER - 1) tn = N_ITER - 1;
    if (act) {                               // prefetch t+2
      size_t a = (size_t)tn * NBINS + k;
      tr1 = tfr[a]; ti1 = tfi[a]; p1 = P[a];
    }
    float Vr = 0.0f, Vi = 0.0f;
    if (act) {
      float Ur = Cr + pc.x, Ui = Ci + pc.y;
      Vr = trc * Ur - tic * Ui;
      Vi = trc * Ui + tic * Ur;
      if (k == 0 || k == 256) Vi = 0.0f;     // pocketfft c2r ignores edge imag
      V[pb][k] = make_float2(Vr, Vi);
    }
    __syncthreads();
    if (act) {
      float2 L = (k == 0)   ? V[pb][1]   : V[pb][k - 1];
      float Ly = (k == 0)   ? -L.y : L.y;    // left of DC = conj(V[1])
      float2 R = (k == 256) ? V[pb][255] : V[pb][k + 1];
      float Ry = (k == 256) ? -R.y : R.y;    // right of Nyq = conj(V[255])
      Cr = 0.54f * Vr - 0.23f * (L.x + R.x);
      Ci = 0.54f * Vi - 0.23f * (Ly + Ry);
      if (t >= tprod) Cws[(size_t)t * NBINS + k] = make_float2(Cr, Ci);
    }
    pb ^= 1;
  }
}

// K3a: frame b: blk[b][:] = (b==0 ? 0 : irfft(C[b-1])) + imps_b, stored in
// natural order (coalesced). LDS read is bit-reversed (2-way bank alias, free).
__global__ __launch_bounds__(256) void ks_inv_fft(const float2* __restrict__ Cws,
                                                  const float* __restrict__ noise,
                                                  const float* __restrict__ env,
                                                  float* __restrict__ blk) {
  __shared__ float2 tw[256];
  __shared__ float2 fb[4][FBSZ];
  const int tid = threadIdx.x;
  const int w = tid >> 6, lane = tid & 63;
  if (tid < 256) {
    float ang = -6.28318530717958647692f * (float)tid / 512.0f;
    float sv, cv; sincosf(ang, &sv, &cv);
    tw[tid] = make_float2(cv, sv);
  }
  const int b = blockIdx.x * 4 + w;
  const int row = (b == 0) ? 0 : (b - 1);    // b=0 runs FFT on row 0, discards
  #pragma unroll
  for (int r = 0; r < 5; ++r) {
    int kk = r * 64 + lane;
    if (kk < NBINS) {
      float2 c = Cws[(size_t)row * NBINS + kk];
      float zr = c.x * (1.0f / 512.0f), zi = c.y * (1.0f / 512.0f);
      fb[w][PD(kk)] = make_float2(zr, zi);
      if (kk >= 1 && kk <= 255) fb[w][PD(512 - kk)] = make_float2(zr, -zi);
    }
  }
  __syncthreads();
  dif_stages(fb[w], tw, lane, -1.0f);        // unnormalized IDFT, bitrev order
  const float e = env[b];
  const float e2 = e * e;
  #pragma unroll
  for (int r = 0; r < 8; ++r) {
    int n = r * 64 + lane;                   // natural order, lane-contiguous
    float y = (b == 0) ? 0.0f : fb[w][PD(brev9(n))].x;
    float imp = (2.0f * noise[(size_t)b * BLOCK_N + n] - 1.0f) * e2;
    blk[(size_t)b * BLOCK_N + n] = y + imp;  // coalesced full-line store
  }
}

// K3b: overlap-add, exactly 2 taps per output: out[s] = blk[f][n] + blk[f-1][n+256].
__global__ __launch_bounds__(256) void ks_ola(const float* __restrict__ blk,
                                              float4* __restrict__ out) {
  const int s4 = blockIdx.x * 256 + threadIdx.x;   // float4 index
  const int s = s4 * 4;
  const int f = s >> 8;
  const int n = s & 255;
  float4 v = *(const float4*)(blk + (size_t)f * BLOCK_N + n);
  if (f >= 1) {
    float4 u = *(const float4*)(blk + (size_t)(f - 1) * BLOCK_N + n + 256);
    v.x += u.x; v.y += u.y; v.z += u.z; v.w += u.w;
  }
  out[s4] = v;
}

extern "C" void kernel_launch(void* const* d_in, const int* in_sizes, int n_in,
                              void* d_out, int out_size, void* d_ws, size_t ws_size,
                              hipStream_t stream) {
  (void)in_sizes; (void)n_in; (void)ws_size; (void)out_size;
  const float* noise = (const float*)d_in[1];
  const float* env   = (const float*)d_in[2];
  const float* tfr   = (const float*)d_in[3];
  const float* tfi   = (const float*)d_in[4];
  float* out = (float*)d_out;

  float2* P   = (float2*)d_ws;
  float2* Cws = (float2*)((char*)d_ws + (size_t)N_ITER * NBINS * sizeof(float2));
  float*  blk = (float*)d_ws;   // reuses P region (P dead after K2); 67.1 MB
  // ws requirement: 2 * 32768 * 257 * 8 = 134,742,016 bytes.

  ks_fwd_fft<<<dim3(N_ITER / 4), dim3(256), 0, stream>>>(noise, env, P);
  ks_recur<<<dim3(NCHUNK), dim3(320), 0, stream>>>(tfr, tfi, P, Cws);
  ks_inv_fft<<<dim3(N_ITER / 4), dim3(256), 0, stream>>>(Cws, noise, env, blk);
  ks_ola<<<dim3(OUT_LEN / 4 / 256), dim3(256), 0, stream>>>(blk, (float4*)out);
}

// Round 3
// 275.285 us; speedup vs baseline: 2.4983x; 1.2478x over previous
//
#include <hip/hip_runtime.h>
#include <math.h>

// ---------------------------------------------------------------------------
// KarplusStrong: spectral-domain reformulation.
//   C_t = Wconv3( tf_t ⊙ (C_{t-1} + P_t) ),  P_t = rfft(imps_t)
//   Wconv3(V)[k] = 0.54 V[k] - 0.23 (V[k-1] + V[k+1]) (hermitian edges),
//   Im(V)=0 forced at bins 0,256 (pocketfft c2r ignores edge imag).
// Contraction |A_t| <= 0.283 => 8-step zero-state warmup error ~4e-5.
//
// R2: (a) ks_recur rewritten wave-per-chunk: 4 bins/lane in registers,
//     neighbor conv via __shfl, no LDS, no barriers; FCH=16, KWARM=8.
//     (b) ks_fwd_fft / ks_inv_fft pack TWO real frames per complex FFT
//     (z = a + i b, hermitian split/merge): half the FFTs and barriers.
// Bin-256 invariant: V[256].im forced 0 => C[256].im == 0 forever; right
// neighbor of 256 is conj(V[255]) so C256 = 0.54 V256r - 0.46 V255r.
// ---------------------------------------------------------------------------

#define N_ITER   32768
#define NBINS    257
#define BLOCK_N  512
#define KWARM    8
#define FCH      16
#define NCHUNK   (N_ITER / FCH)     // 2048
#define OUT_LEN  8388608

__device__ __forceinline__ int brev9(int x) { return (int)(__brev((unsigned)x) >> 23); }
__device__ __forceinline__ int PD(int i) { return i + (i >> 4); }
#define FBSZ 544   // PD(511) = 542

// In-place radix-2 DIF, natural in, bit-reversed out. tsign=+1 fwd, -1 inv.
__device__ __forceinline__ void dif_stages(float2* fb, const float2* tw, int lane, float tsign) {
  #pragma unroll
  for (int s = 8; s >= 0; --s) {
    const int m = 1 << s;
    #pragma unroll
    for (int r = 0; r < 4; ++r) {
      int p = r * 64 + lane;
      int q = p & (m - 1);
      int i = ((p >> s) << (s + 1)) + q;
      float2 a = fb[PD(i)];
      float2 c = fb[PD(i + m)];
      fb[PD(i)] = make_float2(a.x + c.x, a.y + c.y);
      float dr = a.x - c.x, di = a.y - c.y;
      float2 t = tw[q << (8 - s)];
      float twr = t.x, twi = tsign * t.y;
      fb[PD(i + m)] = make_float2(dr * twr - di * twi, dr * twi + di * twr);
    }
    __syncthreads();
  }
}

// K1: wave g packs frames (2g, 2g+1) into one complex FFT; hermitian split
// recovers both rffts. 16384 waves total.
__global__ __launch_bounds__(256) void ks_fwd_fft(const float* __restrict__ noise,
                                                  const float* __restrict__ env,
                                                  float2* __restrict__ P) {
  __shared__ float2 tw[256];
  __shared__ float2 fb[4][FBSZ];
  const int tid = threadIdx.x;
  const int w = tid >> 6, lane = tid & 63;
  if (tid < 256) {
    float ang = -6.28318530717958647692f * (float)tid / 512.0f;
    float sv, cv; sincosf(ang, &sv, &cv);
    tw[tid] = make_float2(cv, sv);
  }
  const int g = blockIdx.x * 4 + w;
  const int fa = 2 * g, fbi = 2 * g + 1;
  const float ea = env[fa];  const float ea2 = ea * ea;
  const float eb = env[fbi]; const float eb2 = eb * eb;
  const float4* na = (const float4*)(noise + (size_t)fa  * BLOCK_N);
  const float4* nb = (const float4*)(noise + (size_t)fbi * BLOCK_N);
  #pragma unroll
  for (int r = 0; r < 2; ++r) {
    int m = r * 64 + lane;             // float4 index 0..127
    float4 A = na[m], B = nb[m];
    int n = 4 * m;
    fb[w][PD(n + 0)] = make_float2((2.f*A.x - 1.f)*ea2, (2.f*B.x - 1.f)*eb2);
    fb[w][PD(n + 1)] = make_float2((2.f*A.y - 1.f)*ea2, (2.f*B.y - 1.f)*eb2);
    fb[w][PD(n + 2)] = make_float2((2.f*A.z - 1.f)*ea2, (2.f*B.z - 1.f)*eb2);
    fb[w][PD(n + 3)] = make_float2((2.f*A.w - 1.f)*ea2, (2.f*B.w - 1.f)*eb2);
  }
  __syncthreads();
  dif_stages(fb[w], tw, lane, 1.0f);
  #pragma unroll
  for (int r = 0; r < 5; ++r) {
    int k = r * 64 + lane;
    if (k < NBINS) {
      float2 Z = fb[w][PD(brev9(k))];
      float2 M = fb[w][PD(brev9((512 - k) & 511))];
      P[(size_t)fa  * NBINS + k] = make_float2(0.5f*(Z.x + M.x), 0.5f*(Z.y - M.y));
      P[(size_t)fbi * NBINS + k] = make_float2(0.5f*(Z.y + M.y), 0.5f*(M.x - Z.x));
    }
  }
}

// K2: one wave per chunk; lane holds bins 4l..4l+3, lane 63 also bin 256.
// Neighbor conv via shfl; depth-2 register prefetch; no LDS, no barriers.
__global__ __launch_bounds__(64) void ks_recur(const float* __restrict__ tfr,
                                               const float* __restrict__ tfi,
                                               const float2* __restrict__ P,
                                               float2* __restrict__ Cws) {
  const int j = blockIdx.x;
  const int lane = threadIdx.x;
  const int k0 = lane * 4;
  const bool l63 = (lane == 63);
  const int tprod = j * FCH;
  const int t0 = (j == 0) ? 0 : (tprod - KWARM);
  const int tend = tprod + FCH;

  float Cr[4] = {0.f,0.f,0.f,0.f}, Ci[4] = {0.f,0.f,0.f,0.f};
  float C256 = 0.f;
  float tr[2][4], ti[2][4], pr[2][4], pi[2][4];
  float t6r[2] = {0.f,0.f}, t6i[2] = {0.f,0.f}, p6r[2] = {0.f,0.f}, p6i[2] = {0.f,0.f};

#define LOADSLOT(S, TS) do {                                                   \
    const size_t _bt = (size_t)(TS) * NBINS;                                   \
    _Pragma("unroll") for (int _i = 0; _i < 4; ++_i) {                         \
      tr[S][_i] = tfr[_bt + k0 + _i];                                          \
      ti[S][_i] = tfi[_bt + k0 + _i];                                          \
      float2 _p = P[_bt + k0 + _i];                                            \
      pr[S][_i] = _p.x; pi[S][_i] = _p.y;                                      \
    }                                                                          \
    if (l63) {                                                                 \
      t6r[S] = tfr[_bt + 256]; t6i[S] = tfi[_bt + 256];                        \
      float2 _q = P[_bt + 256]; p6r[S] = _q.x; p6i[S] = _q.y;                  \
    }                                                                          \
  } while (0)

#define STEP(S, T) do {                                                        \
    const int _t = (T);                                                        \
    float trc[4], tic[4], pcr[4], pci[4];                                      \
    _Pragma("unroll") for (int _i = 0; _i < 4; ++_i) {                         \
      trc[_i] = tr[S][_i]; tic[_i] = ti[S][_i];                                \
      pcr[_i] = pr[S][_i]; pci[_i] = pi[S][_i];                                \
    }                                                                          \
    float tc6r = t6r[S], tc6i = t6i[S], pc6r = p6r[S], pc6i = p6i[S];          \
    int _tn = _t + 2; if (_tn > N_ITER - 1) _tn = N_ITER - 1;                  \
    LOADSLOT(S, _tn);                                                          \
    float Vr[4], Vi[4];                                                        \
    _Pragma("unroll") for (int _i = 0; _i < 4; ++_i) {                         \
      float Ur = Cr[_i] + pcr[_i], Ui = Ci[_i] + pci[_i];                      \
      Vr[_i] = trc[_i]*Ur - tic[_i]*Ui;                                        \
      Vi[_i] = trc[_i]*Ui + tic[_i]*Ur;                                        \
    }                                                                          \
    if (lane == 0) Vi[0] = 0.f;                                                \
    float U6r = C256 + pc6r, U6i = pc6i;                                       \
    float V6r = tc6r*U6r - tc6i*U6i;                                           \
    float Lr = __shfl_up(Vr[3], 1),   Li = __shfl_up(Vi[3], 1);                \
    float Rr = __shfl_down(Vr[0], 1), Ri = __shfl_down(Vi[0], 1);              \
    if (lane == 0) { Lr = Vr[1]; Li = -Vi[1]; }                                \
    if (l63)       { Rr = V6r;   Ri = 0.f; }                                   \
    float n0r = 0.54f*Vr[0] - 0.23f*(Lr    + Vr[1]);                           \
    float n0i = 0.54f*Vi[0] - 0.23f*(Li    + Vi[1]);                           \
    float n1r = 0.54f*Vr[1] - 0.23f*(Vr[0] + Vr[2]);                           \
    float n1i = 0.54f*Vi[1] - 0.23f*(Vi[0] + Vi[2]);                           \
    float n2r = 0.54f*Vr[2] - 0.23f*(Vr[1] + Vr[3]);                           \
    float n2i = 0.54f*Vi[2] - 0.23f*(Vi[1] + Vi[3]);                           \
    float n3r = 0.54f*Vr[3] - 0.23f*(Vr[2] + Rr);                              \
    float n3i = 0.54f*Vi[3] - 0.23f*(Vi[2] + Ri);                              \
    Cr[0]=n0r; Ci[0]=n0i; Cr[1]=n1r; Ci[1]=n1i;                                \
    Cr[2]=n2r; Ci[2]=n2i; Cr[3]=n3r; Ci[3]=n3i;                                \
    C256 = 0.54f*V6r - 0.46f*Vr[3];                                            \
    if (_t >= tprod) {                                                         \
      const size_t _bo = (size_t)_t * NBINS + k0;                              \
      Cws[_bo + 0] = make_float2(Cr[0], Ci[0]);                                \
      Cws[_bo + 1] = make_float2(Cr[1], Ci[1]);                                \
      Cws[_bo + 2] = make_float2(Cr[2], Ci[2]);                                \
      Cws[_bo + 3] = make_float2(Cr[3], Ci[3]);                                \
      if (l63) Cws[(size_t)_t * NBINS + 256] = make_float2(C256, 0.f);         \
    }                                                                          \
  } while (0)

  LOADSLOT(0, t0);
  LOADSLOT(1, t0 + 1);
  for (int t = t0; t < tend; t += 2) {   // (tend-t0) is even for all chunks
    STEP(0, t);
    STEP(1, t + 1);
  }
#undef LOADSLOT
#undef STEP
}

// K3a: wave u packs output frames (2u, 2u+1): Z = SA + i*SB (hermitian ext),
// one inverse FFT gives both irffts (real/imag parts). Frame 0's spectrum is
// zeroed -> its real part is exactly 0. Adds impulses, stores coalesced.
__global__ __launch_bounds__(256) void ks_inv_fft(const float2* __restrict__ Cws,
                                                  const float* __restrict__ noise,
                                                  const float* __restrict__ env,
                                                  float* __restrict__ blk) {
  __shared__ float2 tw[256];
  __shared__ float2 fb[4][FBSZ];
  const int tid = threadIdx.x;
  const int w = tid >> 6, lane = tid & 63;
  if (tid < 256) {
    float ang = -6.28318530717958647692f * (float)tid / 512.0f;
    float sv, cv; sincosf(ang, &sv, &cv);
    tw[tid] = make_float2(cv, sv);
  }
  const int u = blockIdx.x * 4 + w;
  const int fa = 2 * u, fbi = 2 * u + 1;
  const int rowA = (u == 0) ? 0 : (2 * u - 1);   // spectrum for frame fa
  const int rowB = 2 * u;                        // spectrum for frame fbi
  const bool zeroA = (u == 0);
  #pragma unroll
  for (int r = 0; r < 5; ++r) {
    int k = r * 64 + lane;
    if (k < NBINS) {
      float2 a = zeroA ? make_float2(0.f, 0.f) : Cws[(size_t)rowA * NBINS + k];
      float2 b = Cws[(size_t)rowB * NBINS + k];
      const float s = 1.0f / 512.0f;
      float ar = a.x * s, ai = a.y * s, br = b.x * s, bi = b.y * s;
      fb[w][PD(k)] = make_float2(ar - bi, ai + br);
      if (k >= 1 && k <= 255)
        fb[w][PD(512 - k)] = make_float2(ar + bi, br - ai);
    }
  }
  __syncthreads();
  dif_stages(fb[w], tw, lane, -1.0f);
  const float ea = env[fa];  const float ea2 = ea * ea;
  const float eb = env[fbi]; const float eb2 = eb * eb;
  const float4* na = (const float4*)(noise + (size_t)fa  * BLOCK_N);
  const float4* nb = (const float4*)(noise + (size_t)fbi * BLOCK_N);
  float4* oa = (float4*)(blk + (size_t)fa  * BLOCK_N);
  float4* ob = (float4*)(blk + (size_t)fbi * BLOCK_N);
  #pragma unroll
  for (int r = 0; r < 2; ++r) {
    int m = r * 64 + lane;             // float4 index
    float4 A = na[m], B = nb[m];
    int n = 4 * m;
    float2 z0 = fb[w][PD(brev9(n + 0))];
    float2 z1 = fb[w][PD(brev9(n + 1))];
    float2 z2 = fb[w][PD(brev9(n + 2))];
    float2 z3 = fb[w][PD(brev9(n + 3))];
    float4 ya, yb;
    ya.x = z0.x + (2.f*A.x - 1.f)*ea2;  yb.x = z0.y + (2.f*B.x - 1.f)*eb2;
    ya.y = z1.x + (2.f*A.y - 1.f)*ea2;  yb.y = z1.y + (2.f*B.y - 1.f)*eb2;
    ya.z = z2.x + (2.f*A.z - 1.f)*ea2;  yb.z = z2.y + (2.f*B.z - 1.f)*eb2;
    ya.w = z3.x + (2.f*A.w - 1.f)*ea2;  yb.w = z3.y + (2.f*B.w - 1.f)*eb2;
    oa[m] = ya;  ob[m] = yb;
  }
}

// K3b: overlap-add, 2 taps per output: out[s] = blk[f][n] + blk[f-1][n+256].
__global__ __launch_bounds__(256) void ks_ola(const float* __restrict__ blk,
                                              float4* __restrict__ out) {
  const int s4 = blockIdx.x * 256 + threadIdx.x;
  const int s = s4 * 4;
  const int f = s >> 8;
  const int n = s & 255;
  float4 v = *(const float4*)(blk + (size_t)f * BLOCK_N + n);
  if (f >= 1) {
    float4 u = *(const float4*)(blk + (size_t)(f - 1) * BLOCK_N + n + 256);
    v.x += u.x; v.y += u.y; v.z += u.z; v.w += u.w;
  }
  out[s4] = v;
}

extern "C" void kernel_launch(void* const* d_in, const int* in_sizes, int n_in,
                              void* d_out, int out_size, void* d_ws, size_t ws_size,
                              hipStream_t stream) {
  (void)in_sizes; (void)n_in; (void)ws_size; (void)out_size;
  const float* noise = (const float*)d_in[1];
  const float* env   = (const float*)d_in[2];
  const float* tfr   = (const float*)d_in[3];
  const float* tfi   = (const float*)d_in[4];
  float* out = (float*)d_out;

  float2* P   = (float2*)d_ws;
  float2* Cws = (float2*)((char*)d_ws + (size_t)N_ITER * NBINS * sizeof(float2));
  float*  blk = (float*)d_ws;   // reuses P region (P dead after K2); 67.1 MB
  // ws requirement: 2 * 32768 * 257 * 8 = 134,742,016 bytes.

  ks_fwd_fft<<<dim3(N_ITER / 8), dim3(256), 0, stream>>>(noise, env, P);
  ks_recur<<<dim3(NCHUNK), dim3(64), 0, stream>>>(tfr, tfi, P, Cws);
  ks_inv_fft<<<dim3(N_ITER / 8), dim3(256), 0, stream>>>(Cws, noise, env, blk);
  ks_ola<<<dim3(OUT_LEN / 4 / 256), dim3(256), 0, stream>>>(blk, (float4*)out);
}